// Round 12
// baseline (274.567 us; speedup 1.0000x reference)
//
#include <hip/hip_runtime.h>
#include <hip/hip_bf16.h>

typedef __bf16 bf16_t;
typedef __bf16 bf16x8 __attribute__((ext_vector_type(8)));
typedef __bf16 bf16x4 __attribute__((ext_vector_type(4)));
typedef float floatx4 __attribute__((ext_vector_type(4)));
typedef short short4v __attribute__((ext_vector_type(4)));

#define D_MODEL 1024
#define SEQ     2048
#define BATCH   2
#define NHEAD   16
#define HDIM    64
#define MTOT    (BATCH * SEQ)   /* 4096 */

// 1/sqrt(64) * log2(e): exp2(s) == exp(s/8) with this folded into Q
#define QSCALE  0.18033688011112042f

union PBu { bf16x4 b; short4v s; };

__device__ __forceinline__ void async_copy16(const bf16_t* g, bf16_t* l) {
    __builtin_amdgcn_global_load_lds(
        (const __attribute__((address_space(1))) void*)g,
        (__attribute__((address_space(3))) void*)l, 16, 0, 0);
}

// ---------------- prep: x f32->bf16 (z=4) + 4x W transpose (z=0..3) ----------------
__global__ void prep(
    const float* __restrict__ x, bf16_t* __restrict__ xb,
    const float* __restrict__ W0, const float* __restrict__ W1,
    const float* __restrict__ W2, const float* __restrict__ W3,
    bf16_t* __restrict__ T0, bf16_t* __restrict__ T1,
    bf16_t* __restrict__ T2, bf16_t* __restrict__ T3)
{
    __shared__ float tile[32][33];
    const int z = blockIdx.z;
    const int tx = threadIdx.x, ty = threadIdx.y;
    if (z == 4) {
        const int tid = ty * 32 + tx;
        const int base = (blockIdx.y * 32 + blockIdx.x) * 4096 + tid * 4;
#pragma unroll
        for (int r = 0; r < 4; ++r) {
            const int i = base + r * 1024;
            const float4 v = *(const float4*)(x + i);
            bf16x4 o = { (bf16_t)v.x, (bf16_t)v.y, (bf16_t)v.z, (bf16_t)v.w };
            *(bf16x4*)(xb + i) = o;
        }
        return;
    }
    const float* W = (z == 0) ? W0 : (z == 1) ? W1 : (z == 2) ? W2 : W3;
    bf16_t*     Wt = (z == 0) ? T0 : (z == 1) ? T1 : (z == 2) ? T2 : T3;
    const int k0 = blockIdx.y * 32, n0 = blockIdx.x * 32;
#pragma unroll
    for (int j = 0; j < 32; j += 8)
        tile[ty + j][tx] = W[(size_t)(k0 + ty + j) * D_MODEL + n0 + tx];
    __syncthreads();
#pragma unroll
    for (int j = 0; j < 32; j += 8)
        Wt[(size_t)(n0 + ty + j) * D_MODEL + k0 + tx] = (bf16_t)tile[tx][ty + j];
}

// ---------------- 128x128 GEMM mainloop (global_load_lds + XOR swizzle) ----------------
// 768-block config -> 3 blocks/CU co-resident: inter-block wave overlap hides
// the per-K-step barrier drain (m97/m114 structure). Measured best for qkv.
__device__ __forceinline__ void gemm_mainloop(
    const bf16_t* __restrict__ A, const bf16_t* __restrict__ Bt,
    int m0, int n0, bf16_t* As, bf16_t* Bs, floatx4 acc[4][4])
{
    const int tid  = threadIdx.x;
    const int lane = tid & 63;
    const int wid  = tid >> 6;
    const int quad = lane >> 4;
    const int col  = lane & 15;
    const int wm   = (wid >> 1) * 64;
    const int wn   = (wid & 1) * 64;
    const int srow = tid >> 3;                       // 0..31
    const int scc  = ((tid & 7) ^ (srow & 7)) * 8;   // swizzled source col chunk
    const int xorc = col & 7;

    const bf16_t* Ag = A  + (size_t)(m0 + srow) * D_MODEL + scc;
    const bf16_t* Bg = Bt + (size_t)(n0 + srow) * D_MODEL + scc;
    bf16_t* Al = As + tid * 8;
    bf16_t* Bl = Bs + tid * 8;

    for (int kb = 0; kb < D_MODEL; kb += 64) {
#pragma unroll
        for (int p = 0; p < 4; ++p) {
            async_copy16(Ag + kb + p * (32 * D_MODEL), Al + p * 2048);
            async_copy16(Bg + kb + p * (32 * D_MODEL), Bl + p * 2048);
        }
        __syncthreads();
#pragma unroll
        for (int kh = 0; kh < 2; ++kh) {
            bf16x8 af[4], bfr[4];
#pragma unroll
            for (int i = 0; i < 4; ++i)
                af[i] = *(const bf16x8*)(As + (wm + i * 16 + col) * 64 + (((kh * 4 + quad) ^ xorc) * 8));
#pragma unroll
            for (int j = 0; j < 4; ++j)
                bfr[j] = *(const bf16x8*)(Bs + (wn + j * 16 + col) * 64 + (((kh * 4 + quad) ^ xorc) * 8));
#pragma unroll
            for (int i = 0; i < 4; ++i)
#pragma unroll
                for (int j = 0; j < 4; ++j)
                    acc[i][j] = __builtin_amdgcn_mfma_f32_16x16x32_bf16(af[i], bfr[j], acc[i][j], 0, 0, 0);
        }
        __syncthreads();
    }
}

// ---------------- QKV GEMM: grid (8, 32, 3), 128x128 tiles ----------------
__global__ __launch_bounds__(256, 3) void gemm_qkv(
    const bf16_t* __restrict__ xb,
    const bf16_t* __restrict__ Wtq, const bf16_t* __restrict__ Wtk, const bf16_t* __restrict__ Wtv,
    const float* __restrict__ bq, const float* __restrict__ bk, const float* __restrict__ bv,
    bf16_t* __restrict__ Q, bf16_t* __restrict__ Kh, bf16_t* __restrict__ Vt)
{
    __shared__ bf16_t As[128 * 64];
    __shared__ bf16_t Bs[128 * 64];
    const int z = blockIdx.z;
    const bf16_t* Bt   = (z == 0) ? Wtq : (z == 1) ? Wtk : Wtv;
    const float*  bias = (z == 0) ? bq  : (z == 1) ? bk  : bv;
    bf16_t*       O    = (z == 0) ? Q   : (z == 1) ? Kh  : Vt;
    const float   qs   = (z == 0) ? QSCALE : 1.0f;
    const int m0 = blockIdx.y * 128;
    const int n0 = blockIdx.x * 128;

    floatx4 acc[4][4];
#pragma unroll
    for (int i = 0; i < 4; ++i)
#pragma unroll
        for (int j = 0; j < 4; ++j)
            acc[i][j] = (floatx4){0.f, 0.f, 0.f, 0.f};

    gemm_mainloop(xb, Bt, m0, n0, As, Bs, acc);

    const int tid  = threadIdx.x;
    const int lane = tid & 63;
    const int wid  = tid >> 6;
    const int quad = lane >> 4;
    const int col  = lane & 15;
    const int wm   = (wid >> 1) * 64;
    const int wn   = (wid & 1) * 64;

    if (z == 2) {
        // Vt[b,h,d,s]: 4 consecutive s per lane -> bf16x4 stores
#pragma unroll
        for (int i = 0; i < 4; ++i) {
#pragma unroll
            for (int j = 0; j < 4; ++j) {
                const int n = n0 + wn + j * 16 + col;
                const float bb = bias[n];
                const int mb = m0 + wm + i * 16 + quad * 4;
                const size_t bhb = (size_t)((mb >> 11) * NHEAD + (n >> 6)) * (SEQ * HDIM);
                bf16x4 pk = { (bf16_t)(acc[i][j][0] + bb), (bf16_t)(acc[i][j][1] + bb),
                              (bf16_t)(acc[i][j][2] + bb), (bf16_t)(acc[i][j][3] + bb) };
                *(bf16x4*)(O + bhb + (size_t)(n & 63) * SEQ + (mb & 2047)) = pk;
            }
        }
    } else {
#pragma unroll
        for (int i = 0; i < 4; ++i) {
#pragma unroll
            for (int j = 0; j < 4; ++j) {
                const int n = n0 + wn + j * 16 + col;
                const float bb = bias[n];
#pragma unroll
                for (int r = 0; r < 4; ++r) {
                    const int m = m0 + wm + i * 16 + quad * 4 + r;
                    const float v = (acc[i][j][r] + bb) * qs;
                    const size_t bhb = (size_t)((m >> 11) * NHEAD + (n >> 6)) * (SEQ * HDIM);
                    O[bhb + (size_t)(m & 2047) * HDIM + (n & 63)] = (bf16_t)v;
                }
            }
        }
    }
}

// ---------------- flash attention, S^T formulation ----------------
// v12 = v6 (2-D wave partition, deferred PV, stage-after-step) with HALF the
//     barrier joins: 4 LDS tile-buffers; each barrier-pair covers TWO 64-k
//     tiles (step, step) and stages the next pair. vmcnt(8) = the pair about
//     to be read landed; only the most-recent staged pair stays in flight.
//     tilestep/pv bodies and epilogue byte-identical to v6 (verified r5-r11).
//     Grid 512 (XCD-swizzled), 256 thr, LDS 64 KB -> 2 blocks/CU.
__global__ __launch_bounds__(256, 2) void attn_kernel(
    const bf16_t* __restrict__ Q, const bf16_t* __restrict__ K,
    const bf16_t* __restrict__ Vt, bf16_t* __restrict__ A2)
{
    __shared__ union SM {
        struct { bf16_t Ks[4][64 * 64]; bf16_t Vs[4][64 * 64]; } t;   // 64 KB
        struct { float Ored[2][64 * 68]; float Lred[2][64]; } r;      // 35.3 KB
    } sm;

    const int tid  = threadIdx.x;
    const int lane = tid & 63;
    const int wid  = tid >> 6;
    const int quad = lane >> 4;
    const int col  = lane & 15;
    const int xorc = col & 7;
    const int qh   = wid & 1;      // q-half: rows qh*64 .. +63 of the 128 q-tile
    const int kh   = wid >> 1;     // k-half: rows kh*32 .. +31 of each 64-k tile

    const int blk = blockIdx.x;          // 0..511
    const int idx = blk >> 3;            // 0..63
    const int bh  = (blk & 7) * 4 + (idx >> 4);
    const int q0  = (idx & 15) * 128;
    const int b   = bh >> 4, h = bh & 15;

    const bf16_t* Qb = Q  + (size_t)bh * (SEQ * HDIM);
    const bf16_t* Kb = K  + (size_t)bh * (SEQ * HDIM);
    const bf16_t* Vb = Vt + (size_t)bh * (SEQ * HDIM);  // [d][s]

    // Q B-fragments for the wave's 4 q-groups (scale folded in)
    bf16x8 qf[4][2];
#pragma unroll
    for (int g = 0; g < 4; ++g) {
        const int qrow = q0 + qh * 64 + g * 16 + col;
        qf[g][0] = *(const bf16x8*)(Qb + (size_t)qrow * HDIM + quad * 8);
        qf[g][1] = *(const bf16x8*)(Qb + (size_t)qrow * HDIM + 32 + quad * 8);
    }

    floatx4 o_acc[4][4];   // [g][dt]: O^T k-partial
    float lsum[4] = {0.f, 0.f, 0.f, 0.f};
#pragma unroll
    for (int g = 0; g < 4; ++g)
#pragma unroll
        for (int dt = 0; dt < 4; ++dt)
            o_acc[g][dt] = (floatx4){0.f, 0.f, 0.f, 0.f};

    const int srow = tid >> 3;                          // 0..31
    const int scc  = ((tid & 7) ^ (srow & 7)) * 8;
    const bf16_t* Kg = Kb + (size_t)srow * HDIM + scc;
    const bf16_t* Vg = Vb + (size_t)srow * SEQ + scc;
    bf16_t* Ks0 = &sm.t.Ks[0][0];
    bf16_t* Ks1 = &sm.t.Ks[1][0];
    bf16_t* Ks2 = &sm.t.Ks[2][0];
    bf16_t* Ks3 = &sm.t.Ks[3][0];
    bf16_t* Vs0 = &sm.t.Vs[0][0];
    bf16_t* Vs1 = &sm.t.Vs[1][0];
    bf16_t* Vs2 = &sm.t.Vs[2][0];
    bf16_t* Vs3 = &sm.t.Vs[3][0];

    auto stage = [&](int ko, bf16_t* dk, bf16_t* dv) {
        async_copy16(Kg + (size_t)ko * HDIM, dk + tid * 8);
        async_copy16(Kg + (size_t)(ko + 32) * HDIM, dk + tid * 8 + 2048);
        async_copy16(Vg + ko, dv + tid * 8);
        async_copy16(Vg + (size_t)32 * SEQ + ko, dv + tid * 8 + 2048);
    };

    short4v vfrA[4][2], vfrB[4][2];
    short4v pbA[4][2],  pbB[4][2];

    auto pv = [&](short4v (&vfrP)[4][2], short4v (&pbP)[4][2]) {
        __builtin_amdgcn_s_setprio(1);
#pragma unroll
        for (int g = 0; g < 4; ++g)
#pragma unroll
            for (int dt = 0; dt < 4; ++dt)
#pragma unroll
                for (int tt = 0; tt < 2; ++tt)
                    o_acc[g][dt] = __builtin_amdgcn_mfma_f32_16x16x16bf16_1k(
                        vfrP[dt][tt], pbP[g][tt], o_acc[g][dt], 0, 0, 0);
        __builtin_amdgcn_s_setprio(0);
    };

    auto tilestep = [&](const bf16_t* KsC, const bf16_t* VsC,
                        short4v (&vfrC)[4][2], short4v (&pbC)[4][2],
                        short4v (&vfrP)[4][2], short4v (&pbP)[4][2],
                        bool doPV) {
        bf16x8 kf[2][2];
#pragma unroll
        for (int tt = 0; tt < 2; ++tt) {
            const int t = kh * 2 + tt;
            kf[tt][0] = *(const bf16x8*)(KsC + (t * 16 + col) * 64 + ((quad ^ xorc) * 8));
            kf[tt][1] = *(const bf16x8*)(KsC + (t * 16 + col) * 64 + (((4 + quad) ^ xorc) * 8));
        }
#pragma unroll
        for (int dt = 0; dt < 4; ++dt)
#pragma unroll
            for (int tt = 0; tt < 2; ++tt) {
                const int t = kh * 2 + tt;
                const int sch = t * 2 + (quad >> 1);
                vfrC[dt][tt] = *(const short4v*)(VsC + (dt * 16 + col) * 64 + ((sch ^ xorc) * 8) + (quad & 1) * 4);
            }
        if (doPV) pv(vfrP, pbP);
#pragma unroll
        for (int g = 0; g < 4; ++g) {
            floatx4 s_acc[2];
            __builtin_amdgcn_s_setprio(1);
#pragma unroll
            for (int tt = 0; tt < 2; ++tt) {
                s_acc[tt] = (floatx4){0.f, 0.f, 0.f, 0.f};
                s_acc[tt] = __builtin_amdgcn_mfma_f32_16x16x32_bf16(kf[tt][0], qf[g][0], s_acc[tt], 0, 0, 0);
                s_acc[tt] = __builtin_amdgcn_mfma_f32_16x16x32_bf16(kf[tt][1], qf[g][1], s_acc[tt], 0, 0, 0);
            }
            __builtin_amdgcn_s_setprio(0);
            float ls = 0.f;
#pragma unroll
            for (int tt = 0; tt < 2; ++tt) {
                const float p0 = __builtin_amdgcn_exp2f(s_acc[tt][0]);
                const float p1 = __builtin_amdgcn_exp2f(s_acc[tt][1]);
                const float p2 = __builtin_amdgcn_exp2f(s_acc[tt][2]);
                const float p3 = __builtin_amdgcn_exp2f(s_acc[tt][3]);
                ls += (p0 + p1) + (p2 + p3);
                PBu u;
                u.b = (bf16x4){ (bf16_t)p0, (bf16_t)p1, (bf16_t)p2, (bf16_t)p3 };
                pbC[g][tt] = u.s;
            }
            lsum[g] += ls;
        }
    };

    // prologue: tiles 0..3 -> bufs 0..3 (16 outstanding loads/thread)
    stage(0,       Ks0, Vs0);
    stage(64,      Ks1, Vs1);
    stage(2 * 64,  Ks2, Vs2);
    stage(3 * 64,  Ks3, Vs3);

    // h=0: tiles 0,1 (bufs 0,1); vmcnt(8) -> tiles 2,3 may stay in flight
    asm volatile("s_waitcnt vmcnt(8)" ::: "memory");
    __builtin_amdgcn_s_barrier();
    tilestep(Ks0, Vs0, vfrA, pbA, vfrB, pbB, false);   // tile 0 -> A
    tilestep(Ks1, Vs1, vfrB, pbB, vfrA, pbA, true);    // tile 1 -> B, PV(0)
    asm volatile("s_waitcnt lgkmcnt(0)" ::: "memory");
    __builtin_amdgcn_s_barrier();
    stage(4 * 64, Ks0, Vs0);
    stage(5 * 64, Ks1, Vs1);

    // steady state: each half-iteration = one barrier-pair covering 2 tiles.
#pragma unroll 1
    for (int hh = 0; hh < 7; ++hh) {
        // tiles 4hh+2, 4hh+3 (bufs 2,3); stage tiles 4hh+6, 4hh+7
        asm volatile("s_waitcnt vmcnt(8)" ::: "memory");
        __builtin_amdgcn_s_barrier();
        tilestep(Ks2, Vs2, vfrA, pbA, vfrB, pbB, true);
        tilestep(Ks3, Vs3, vfrB, pbB, vfrA, pbA, true);
        asm volatile("s_waitcnt lgkmcnt(0)" ::: "memory");
        __builtin_amdgcn_s_barrier();
        stage((4 * hh + 6) * 64, Ks2, Vs2);
        stage((4 * hh + 7) * 64, Ks3, Vs3);

        // tiles 4hh+4, 4hh+5 (bufs 0,1); stage tiles 4hh+8, 4hh+9 (if any)
        asm volatile("s_waitcnt vmcnt(8)" ::: "memory");
        __builtin_amdgcn_s_barrier();
        tilestep(Ks0, Vs0, vfrA, pbA, vfrB, pbB, true);
        tilestep(Ks1, Vs1, vfrB, pbB, vfrA, pbA, true);
        asm volatile("s_waitcnt lgkmcnt(0)" ::: "memory");
        __builtin_amdgcn_s_barrier();
        if (hh < 6) {
            stage((4 * hh + 8) * 64, Ks0, Vs0);
            stage((4 * hh + 9) * 64, Ks1, Vs1);
        }
    }
    // tail: tiles 30,31 (bufs 2,3); drain
    asm volatile("s_waitcnt vmcnt(0)" ::: "memory");
    __builtin_amdgcn_s_barrier();
    tilestep(Ks2, Vs2, vfrA, pbA, vfrB, pbB, true);    // tile 30 -> A
    tilestep(Ks3, Vs3, vfrB, pbB, vfrA, pbA, true);    // tile 31 -> B
    pv(vfrB, pbB);                                      // final PV(31)

    // ---- cross-wave reduction: (qh, kh=0) + (qh, kh=1) ----
#pragma unroll
    for (int g = 0; g < 4; ++g) {
        lsum[g] += __shfl_xor(lsum[g], 16, 64);
        lsum[g] += __shfl_xor(lsum[g], 32, 64);
    }
    __syncthreads();
    if (kh == 1) {
#pragma unroll
        for (int g = 0; g < 4; ++g) {
#pragma unroll
            for (int dt = 0; dt < 4; ++dt)
#pragma unroll
                for (int r = 0; r < 4; ++r) {
                    const int d = dt * 16 + quad * 4 + r;
                    sm.r.Ored[qh][d * 68 + g * 16 + col] = o_acc[g][dt][r];
                }
            if (quad == 0)
                sm.r.Lred[qh][g * 16 + col] = lsum[g];
        }
    }
    __syncthreads();
    if (kh == 0) {
#pragma unroll
        for (int g = 0; g < 4; ++g) {
            const float l = lsum[g] + sm.r.Lred[qh][g * 16 + col];
            const float inv = 1.0f / l;
            const int qrow = q0 + qh * 64 + g * 16 + col;
            bf16_t* dst = A2 + ((size_t)(b * SEQ + qrow)) * D_MODEL + h * HDIM + quad * 4;
#pragma unroll
            for (int dt = 0; dt < 4; ++dt) {
                bf16x4 pk;
#pragma unroll
                for (int r = 0; r < 4; ++r) {
                    const int d = dt * 16 + quad * 4 + r;
                    pk[r] = (bf16_t)((o_acc[g][dt][r] + sm.r.Ored[qh][d * 68 + g * 16 + col]) * inv);
                }
                *(bf16x4*)(dst + dt * 16) = pk;
            }
        }
    }
}

// ---------------- output projection: 64x128 tiles, grid (8, 64) ----------------
__global__ __launch_bounds__(256, 3) void gemm_proj(
    const bf16_t* __restrict__ A2, const bf16_t* __restrict__ Wto,
    const float* __restrict__ bo, float* __restrict__ out)
{
    __shared__ bf16_t As[64 * 64];    // 8 KB
    __shared__ bf16_t Bs[128 * 64];   // 16 KB
    const int m0 = blockIdx.y * 64;
    const int n0 = blockIdx.x * 128;

    const int tid  = threadIdx.x;
    const int lane = tid & 63;
    const int wid  = tid >> 6;
    const int quad = lane >> 4;
    const int col  = lane & 15;
    const int wm   = (wid >> 1) * 32;
    const int wn   = (wid & 1) * 64;
    const int srow = tid >> 3;
    const int scc  = ((tid & 7) ^ (srow & 7)) * 8;
    const int xorc = col & 7;

    floatx4 acc[2][4];
#pragma unroll
    for (int i = 0; i < 2; ++i)
#pragma unroll
        for (int j = 0; j < 4; ++j)
            acc[i][j] = (floatx4){0.f, 0.f, 0.f, 0.f};

    const bf16_t* Ag = A2  + (size_t)(m0 + srow) * D_MODEL + scc;
    const bf16_t* Bg = Wto + (size_t)(n0 + srow) * D_MODEL + scc;
    bf16_t* Al = As + tid * 8;
    bf16_t* Bl = Bs + tid * 8;

    for (int kb = 0; kb < D_MODEL; kb += 64) {
#pragma unroll
        for (int p = 0; p < 2; ++p)
            async_copy16(Ag + kb + p * (32 * D_MODEL), Al + p * 2048);
#pragma unroll
        for (int p = 0; p < 4; ++p)
            async_copy16(Bg + kb + p * (32 * D_MODEL), Bl + p * 2048);
        __syncthreads();
#pragma unroll
        for (int kh = 0; kh < 2; ++kh) {
            bf16x8 af[2], bfr[4];
#pragma unroll
            for (int i = 0; i < 2; ++i)
                af[i] = *(const bf16x8*)(As + (wm + i * 16 + col) * 64 + (((kh * 4 + quad) ^ xorc) * 8));
#pragma unroll
            for (int j = 0; j < 4; ++j)
                bfr[j] = *(const bf16x8*)(Bs + (wn + j * 16 + col) * 64 + (((kh * 4 + quad) ^ xorc) * 8));
#pragma unroll
            for (int i = 0; i < 2; ++i)
#pragma unroll
                for (int j = 0; j < 4; ++j)
                    acc[i][j] = __builtin_amdgcn_mfma_f32_16x16x32_bf16(af[i], bfr[j], acc[i][j], 0, 0, 0);
        }
        __syncthreads();
    }

#pragma unroll
    for (int i = 0; i < 2; ++i) {
#pragma unroll
        for (int j = 0; j < 4; ++j) {
            const int n = n0 + wn + j * 16 + col;
            const float bb = bo[n];
#pragma unroll
            for (int r = 0; r < 4; ++r) {
                const int m = m0 + wm + i * 16 + quad * 4 + r;
                out[(size_t)m * D_MODEL + n] = acc[i][j][r] + bb;
            }
        }
    }
}

// ---------------- host ----------------
extern "C" void kernel_launch(void* const* d_in, const int* in_sizes, int n_in,
                              void* d_out, int out_size, void* d_ws, size_t ws_size,
                              hipStream_t stream) {
    const float* x  = (const float*)d_in[0];
    const float* Wq = (const float*)d_in[1];
    const float* bq = (const float*)d_in[2];
    const float* Wk = (const float*)d_in[3];
    const float* bk = (const float*)d_in[4];
    const float* Wv = (const float*)d_in[5];
    const float* bv = (const float*)d_in[6];
    const float* Wo = (const float*)d_in[7];
    const float* bo = (const float*)d_in[8];
    float* out = (float*)d_out;

    const size_t MB = 1ull << 20;
    char* ws = (char*)d_ws;
    bf16_t* Q     = (bf16_t*)(ws + 0 * MB);    // 8 MB  [b,h,s,d]
    bf16_t* Kh    = (bf16_t*)(ws + 8 * MB);    // 8 MB  [b,h,s,d]
    bf16_t* Vt    = (bf16_t*)(ws + 16 * MB);   // 8 MB  [b,h,d,s]
    bf16_t* A2    = (bf16_t*)(ws + 24 * MB);   // 8 MB  [b,s,h*d]
    bf16_t* xb    = (bf16_t*)(ws + 32 * MB);   // 8 MB
    bf16_t* Wtq   = (bf16_t*)(ws + 40 * MB);   // 2 MB each
    bf16_t* Wtk   = (bf16_t*)(ws + 42 * MB);
    bf16_t* Wtv   = (bf16_t*)(ws + 44 * MB);
    bf16_t* Wto   = (bf16_t*)(ws + 46 * MB);

    prep<<<dim3(32, 32, 5), dim3(32, 8), 0, stream>>>(
        x, xb, Wq, Wk, Wv, Wo, Wtq, Wtk, Wtv, Wto);

    gemm_qkv<<<dim3(D_MODEL / 128, MTOT / 128, 3), 256, 0, stream>>>(
        xb, Wtq, Wtk, Wtv, bq, bk, bv, Q, Kh, Vt);

    attn_kernel<<<dim3(512), 256, 0, stream>>>(Q, Kh, Vt, A2);

    gemm_proj<<<dim3(D_MODEL / 128, MTOT / 64), 256, 0, stream>>>(A2, Wto, bo, out);
}

// Round 13
// 179.206 us; speedup vs baseline: 1.5321x; 1.5321x over previous
//
#include <hip/hip_runtime.h>
#include <hip/hip_bf16.h>

typedef __bf16 bf16_t;
typedef __bf16 bf16x8 __attribute__((ext_vector_type(8)));
typedef __bf16 bf16x4 __attribute__((ext_vector_type(4)));
typedef float floatx4 __attribute__((ext_vector_type(4)));
typedef short short4v __attribute__((ext_vector_type(4)));

#define D_MODEL 1024
#define SEQ     2048
#define BATCH   2
#define NHEAD   16
#define HDIM    64
#define MTOT    (BATCH * SEQ)   /* 4096 */

// 1/sqrt(64) * log2(e): exp2(s) == exp(s/8) with this folded into Q
#define QSCALE  0.18033688011112042f

union PBu { bf16x4 b; short4v s; };

__device__ __forceinline__ void async_copy16(const bf16_t* g, bf16_t* l) {
    __builtin_amdgcn_global_load_lds(
        (const __attribute__((address_space(1))) void*)g,
        (__attribute__((address_space(3))) void*)l, 16, 0, 0);
}

// ---------------- prep: x f32->bf16 (z=4) + 4x W transpose (z=0..3) ----------------
__global__ void prep(
    const float* __restrict__ x, bf16_t* __restrict__ xb,
    const float* __restrict__ W0, const float* __restrict__ W1,
    const float* __restrict__ W2, const float* __restrict__ W3,
    bf16_t* __restrict__ T0, bf16_t* __restrict__ T1,
    bf16_t* __restrict__ T2, bf16_t* __restrict__ T3)
{
    __shared__ float tile[32][33];
    const int z = blockIdx.z;
    const int tx = threadIdx.x, ty = threadIdx.y;
    if (z == 4) {
        const int tid = ty * 32 + tx;
        const int base = (blockIdx.y * 32 + blockIdx.x) * 4096 + tid * 4;
#pragma unroll
        for (int r = 0; r < 4; ++r) {
            const int i = base + r * 1024;
            const float4 v = *(const float4*)(x + i);
            bf16x4 o = { (bf16_t)v.x, (bf16_t)v.y, (bf16_t)v.z, (bf16_t)v.w };
            *(bf16x4*)(xb + i) = o;
        }
        return;
    }
    const float* W = (z == 0) ? W0 : (z == 1) ? W1 : (z == 2) ? W2 : W3;
    bf16_t*     Wt = (z == 0) ? T0 : (z == 1) ? T1 : (z == 2) ? T2 : T3;
    const int k0 = blockIdx.y * 32, n0 = blockIdx.x * 32;
#pragma unroll
    for (int j = 0; j < 32; j += 8)
        tile[ty + j][tx] = W[(size_t)(k0 + ty + j) * D_MODEL + n0 + tx];
    __syncthreads();
#pragma unroll
    for (int j = 0; j < 32; j += 8)
        Wt[(size_t)(n0 + ty + j) * D_MODEL + k0 + tx] = (bf16_t)tile[tx][ty + j];
}

// ---------------- 128x128 GEMM mainloop (global_load_lds + XOR swizzle) ----------------
// 768-block config -> 3 blocks/CU co-resident: inter-block wave overlap hides
// the per-K-step barrier drain (m97/m114 structure). Measured best for qkv.
__device__ __forceinline__ void gemm_mainloop(
    const bf16_t* __restrict__ A, const bf16_t* __restrict__ Bt,
    int m0, int n0, bf16_t* As, bf16_t* Bs, floatx4 acc[4][4])
{
    const int tid  = threadIdx.x;
    const int lane = tid & 63;
    const int wid  = tid >> 6;
    const int quad = lane >> 4;
    const int col  = lane & 15;
    const int wm   = (wid >> 1) * 64;
    const int wn   = (wid & 1) * 64;
    const int srow = tid >> 3;                       // 0..31
    const int scc  = ((tid & 7) ^ (srow & 7)) * 8;   // swizzled source col chunk
    const int xorc = col & 7;

    const bf16_t* Ag = A  + (size_t)(m0 + srow) * D_MODEL + scc;
    const bf16_t* Bg = Bt + (size_t)(n0 + srow) * D_MODEL + scc;
    bf16_t* Al = As + tid * 8;
    bf16_t* Bl = Bs + tid * 8;

    for (int kb = 0; kb < D_MODEL; kb += 64) {
#pragma unroll
        for (int p = 0; p < 4; ++p) {
            async_copy16(Ag + kb + p * (32 * D_MODEL), Al + p * 2048);
            async_copy16(Bg + kb + p * (32 * D_MODEL), Bl + p * 2048);
        }
        __syncthreads();
#pragma unroll
        for (int kh = 0; kh < 2; ++kh) {
            bf16x8 af[4], bfr[4];
#pragma unroll
            for (int i = 0; i < 4; ++i)
                af[i] = *(const bf16x8*)(As + (wm + i * 16 + col) * 64 + (((kh * 4 + quad) ^ xorc) * 8));
#pragma unroll
            for (int j = 0; j < 4; ++j)
                bfr[j] = *(const bf16x8*)(Bs + (wn + j * 16 + col) * 64 + (((kh * 4 + quad) ^ xorc) * 8));
#pragma unroll
            for (int i = 0; i < 4; ++i)
#pragma unroll
                for (int j = 0; j < 4; ++j)
                    acc[i][j] = __builtin_amdgcn_mfma_f32_16x16x32_bf16(af[i], bfr[j], acc[i][j], 0, 0, 0);
        }
        __syncthreads();
    }
}

// ---------------- QKV GEMM: grid (8, 32, 3), 128x128 tiles ----------------
__global__ __launch_bounds__(256, 3) void gemm_qkv(
    const bf16_t* __restrict__ xb,
    const bf16_t* __restrict__ Wtq, const bf16_t* __restrict__ Wtk, const bf16_t* __restrict__ Wtv,
    const float* __restrict__ bq, const float* __restrict__ bk, const float* __restrict__ bv,
    bf16_t* __restrict__ Q, bf16_t* __restrict__ Kh, bf16_t* __restrict__ Vt)
{
    __shared__ bf16_t As[128 * 64];
    __shared__ bf16_t Bs[128 * 64];
    const int z = blockIdx.z;
    const bf16_t* Bt   = (z == 0) ? Wtq : (z == 1) ? Wtk : Wtv;
    const float*  bias = (z == 0) ? bq  : (z == 1) ? bk  : bv;
    bf16_t*       O    = (z == 0) ? Q   : (z == 1) ? Kh  : Vt;
    const float   qs   = (z == 0) ? QSCALE : 1.0f;
    const int m0 = blockIdx.y * 128;
    const int n0 = blockIdx.x * 128;

    floatx4 acc[4][4];
#pragma unroll
    for (int i = 0; i < 4; ++i)
#pragma unroll
        for (int j = 0; j < 4; ++j)
            acc[i][j] = (floatx4){0.f, 0.f, 0.f, 0.f};

    gemm_mainloop(xb, Bt, m0, n0, As, Bs, acc);

    const int tid  = threadIdx.x;
    const int lane = tid & 63;
    const int wid  = tid >> 6;
    const int quad = lane >> 4;
    const int col  = lane & 15;
    const int wm   = (wid >> 1) * 64;
    const int wn   = (wid & 1) * 64;

    if (z == 2) {
        // Vt[b,h,d,s]: 4 consecutive s per lane -> bf16x4 stores
#pragma unroll
        for (int i = 0; i < 4; ++i) {
#pragma unroll
            for (int j = 0; j < 4; ++j) {
                const int n = n0 + wn + j * 16 + col;
                const float bb = bias[n];
                const int mb = m0 + wm + i * 16 + quad * 4;
                const size_t bhb = (size_t)((mb >> 11) * NHEAD + (n >> 6)) * (SEQ * HDIM);
                bf16x4 pk = { (bf16_t)(acc[i][j][0] + bb), (bf16_t)(acc[i][j][1] + bb),
                              (bf16_t)(acc[i][j][2] + bb), (bf16_t)(acc[i][j][3] + bb) };
                *(bf16x4*)(O + bhb + (size_t)(n & 63) * SEQ + (mb & 2047)) = pk;
            }
        }
    } else {
#pragma unroll
        for (int i = 0; i < 4; ++i) {
#pragma unroll
            for (int j = 0; j < 4; ++j) {
                const int n = n0 + wn + j * 16 + col;
                const float bb = bias[n];
#pragma unroll
                for (int r = 0; r < 4; ++r) {
                    const int m = m0 + wm + i * 16 + quad * 4 + r;
                    const float v = (acc[i][j][r] + bb) * qs;
                    const size_t bhb = (size_t)((m >> 11) * NHEAD + (n >> 6)) * (SEQ * HDIM);
                    O[bhb + (size_t)(m & 2047) * HDIM + (n & 63)] = (bf16_t)v;
                }
            }
        }
    }
}

// ---------------- flash attention, S^T formulation (v6 = measured best) ------
// 2-D wave partition (q-half x k-half), wave owns 64q x 32k; T15 deferred PV;
// 2-buffer counted vmcnt(4) loop. Grid 512 (XCD-swizzled), 256 thr, 35.3 KB.
// Measured optimum across occupancy {2,3,4 w/SIMD}, barrier count {1,2},
// buffers {2,3,4}, traffic {1x, 0.5x}, q-tile {64,128}, block {256,512 thr}
// (rounds 0-12). Join-halving (r12) is register-infeasible in this family.
__global__ __launch_bounds__(256, 2) void attn_kernel(
    const bf16_t* __restrict__ Q, const bf16_t* __restrict__ K,
    const bf16_t* __restrict__ Vt, bf16_t* __restrict__ A2)
{
    __shared__ union SM {
        struct { bf16_t Ks[2][64 * 64]; bf16_t Vs[2][64 * 64]; } t;   // 32 KB
        struct { float Ored[2][64 * 68]; float Lred[2][64]; } r;      // 35.3 KB
    } sm;

    const int tid  = threadIdx.x;
    const int lane = tid & 63;
    const int wid  = tid >> 6;
    const int quad = lane >> 4;
    const int col  = lane & 15;
    const int xorc = col & 7;
    const int qh   = wid & 1;      // q-half: rows qh*64 .. +63 of the 128 q-tile
    const int kh   = wid >> 1;     // k-half: rows kh*32 .. +31 of each 64-k tile

    const int blk = blockIdx.x;          // 0..511
    const int idx = blk >> 3;            // 0..63
    const int bh  = (blk & 7) * 4 + (idx >> 4);
    const int q0  = (idx & 15) * 128;
    const int b   = bh >> 4, h = bh & 15;

    const bf16_t* Qb = Q  + (size_t)bh * (SEQ * HDIM);
    const bf16_t* Kb = K  + (size_t)bh * (SEQ * HDIM);
    const bf16_t* Vb = Vt + (size_t)bh * (SEQ * HDIM);  // [d][s]

    // Q B-fragments for the wave's 4 q-groups (scale folded in)
    bf16x8 qf[4][2];
#pragma unroll
    for (int g = 0; g < 4; ++g) {
        const int qrow = q0 + qh * 64 + g * 16 + col;
        qf[g][0] = *(const bf16x8*)(Qb + (size_t)qrow * HDIM + quad * 8);
        qf[g][1] = *(const bf16x8*)(Qb + (size_t)qrow * HDIM + 32 + quad * 8);
    }

    floatx4 o_acc[4][4];   // [g][dt]: O^T k-partial
    float lsum[4] = {0.f, 0.f, 0.f, 0.f};
#pragma unroll
    for (int g = 0; g < 4; ++g)
#pragma unroll
        for (int dt = 0; dt < 4; ++dt)
            o_acc[g][dt] = (floatx4){0.f, 0.f, 0.f, 0.f};

    const int srow = tid >> 3;                          // 0..31
    const int scc  = ((tid & 7) ^ (srow & 7)) * 8;
    const bf16_t* Kg = Kb + (size_t)srow * HDIM + scc;
    const bf16_t* Vg = Vb + (size_t)srow * SEQ + scc;
    bf16_t* Ks0 = &sm.t.Ks[0][0];
    bf16_t* Ks1 = &sm.t.Ks[1][0];
    bf16_t* Vs0 = &sm.t.Vs[0][0];
    bf16_t* Vs1 = &sm.t.Vs[1][0];

    auto stage = [&](int ko, bf16_t* dk, bf16_t* dv) {
        async_copy16(Kg + (size_t)ko * HDIM, dk + tid * 8);
        async_copy16(Kg + (size_t)(ko + 32) * HDIM, dk + tid * 8 + 2048);
        async_copy16(Vg + ko, dv + tid * 8);
        async_copy16(Vg + (size_t)32 * SEQ + ko, dv + tid * 8 + 2048);
    };

    short4v vfrA[4][2], vfrB[4][2];
    short4v pbA[4][2],  pbB[4][2];

    auto pv = [&](short4v (&vfrP)[4][2], short4v (&pbP)[4][2]) {
        __builtin_amdgcn_s_setprio(1);
#pragma unroll
        for (int g = 0; g < 4; ++g)
#pragma unroll
            for (int dt = 0; dt < 4; ++dt)
#pragma unroll
                for (int tt = 0; tt < 2; ++tt)
                    o_acc[g][dt] = __builtin_amdgcn_mfma_f32_16x16x16bf16_1k(
                        vfrP[dt][tt], pbP[g][tt], o_acc[g][dt], 0, 0, 0);
        __builtin_amdgcn_s_setprio(0);
    };

    auto tilestep = [&](const bf16_t* KsC, const bf16_t* VsC,
                        short4v (&vfrC)[4][2], short4v (&pbC)[4][2],
                        short4v (&vfrP)[4][2], short4v (&pbP)[4][2],
                        bool doPV) {
        bf16x8 kf[2][2];
#pragma unroll
        for (int tt = 0; tt < 2; ++tt) {
            const int t = kh * 2 + tt;
            kf[tt][0] = *(const bf16x8*)(KsC + (t * 16 + col) * 64 + ((quad ^ xorc) * 8));
            kf[tt][1] = *(const bf16x8*)(KsC + (t * 16 + col) * 64 + (((4 + quad) ^ xorc) * 8));
        }
#pragma unroll
        for (int dt = 0; dt < 4; ++dt)
#pragma unroll
            for (int tt = 0; tt < 2; ++tt) {
                const int t = kh * 2 + tt;
                const int sch = t * 2 + (quad >> 1);
                vfrC[dt][tt] = *(const short4v*)(VsC + (dt * 16 + col) * 64 + ((sch ^ xorc) * 8) + (quad & 1) * 4);
            }
        if (doPV) pv(vfrP, pbP);
#pragma unroll
        for (int g = 0; g < 4; ++g) {
            floatx4 s_acc[2];
            __builtin_amdgcn_s_setprio(1);
#pragma unroll
            for (int tt = 0; tt < 2; ++tt) {
                s_acc[tt] = (floatx4){0.f, 0.f, 0.f, 0.f};
                s_acc[tt] = __builtin_amdgcn_mfma_f32_16x16x32_bf16(kf[tt][0], qf[g][0], s_acc[tt], 0, 0, 0);
                s_acc[tt] = __builtin_amdgcn_mfma_f32_16x16x32_bf16(kf[tt][1], qf[g][1], s_acc[tt], 0, 0, 0);
            }
            __builtin_amdgcn_s_setprio(0);
            float ls = 0.f;
#pragma unroll
            for (int tt = 0; tt < 2; ++tt) {
                const float p0 = __builtin_amdgcn_exp2f(s_acc[tt][0]);
                const float p1 = __builtin_amdgcn_exp2f(s_acc[tt][1]);
                const float p2 = __builtin_amdgcn_exp2f(s_acc[tt][2]);
                const float p3 = __builtin_amdgcn_exp2f(s_acc[tt][3]);
                ls += (p0 + p1) + (p2 + p3);
                PBu u;
                u.b = (bf16x4){ (bf16_t)p0, (bf16_t)p1, (bf16_t)p2, (bf16_t)p3 };
                pbC[g][tt] = u.s;
            }
            lsum[g] += ls;
        }
    };

    stage(0,  Ks0, Vs0);
    stage(64, Ks1, Vs1);

    asm volatile("s_waitcnt vmcnt(4)" ::: "memory");
    __builtin_amdgcn_s_barrier();
    tilestep(Ks0, Vs0, vfrA, pbA, vfrB, pbB, false);
    asm volatile("s_waitcnt lgkmcnt(0)" ::: "memory");
    __builtin_amdgcn_s_barrier();
    stage(2 * 64, Ks0, Vs0);

#pragma unroll 1
    for (int p = 0; p < 15; ++p) {
        asm volatile("s_waitcnt vmcnt(4)" ::: "memory");
        __builtin_amdgcn_s_barrier();
        tilestep(Ks1, Vs1, vfrB, pbB, vfrA, pbA, true);
        asm volatile("s_waitcnt lgkmcnt(0)" ::: "memory");
        __builtin_amdgcn_s_barrier();
        stage((2 * p + 3) * 64, Ks1, Vs1);

        asm volatile("s_waitcnt vmcnt(4)" ::: "memory");
        __builtin_amdgcn_s_barrier();
        tilestep(Ks0, Vs0, vfrA, pbA, vfrB, pbB, true);
        asm volatile("s_waitcnt lgkmcnt(0)" ::: "memory");
        __builtin_amdgcn_s_barrier();
        if (p < 14) stage((2 * p + 4) * 64, Ks0, Vs0);
    }
    asm volatile("s_waitcnt vmcnt(0)" ::: "memory");
    __builtin_amdgcn_s_barrier();
    tilestep(Ks1, Vs1, vfrB, pbB, vfrA, pbA, true);
    pv(vfrB, pbB);

#pragma unroll
    for (int g = 0; g < 4; ++g) {
        lsum[g] += __shfl_xor(lsum[g], 16, 64);
        lsum[g] += __shfl_xor(lsum[g], 32, 64);
    }
    __syncthreads();
    if (kh == 1) {
#pragma unroll
        for (int g = 0; g < 4; ++g) {
#pragma unroll
            for (int dt = 0; dt < 4; ++dt)
#pragma unroll
                for (int r = 0; r < 4; ++r) {
                    const int d = dt * 16 + quad * 4 + r;
                    sm.r.Ored[qh][d * 68 + g * 16 + col] = o_acc[g][dt][r];
                }
            if (quad == 0)
                sm.r.Lred[qh][g * 16 + col] = lsum[g];
        }
    }
    __syncthreads();
    if (kh == 0) {
#pragma unroll
        for (int g = 0; g < 4; ++g) {
            const float l = lsum[g] + sm.r.Lred[qh][g * 16 + col];
            const float inv = 1.0f / l;
            const int qrow = q0 + qh * 64 + g * 16 + col;
            bf16_t* dst = A2 + ((size_t)(b * SEQ + qrow)) * D_MODEL + h * HDIM + quad * 4;
#pragma unroll
            for (int dt = 0; dt < 4; ++dt) {
                bf16x4 pk;
#pragma unroll
                for (int r = 0; r < 4; ++r) {
                    const int d = dt * 16 + quad * 4 + r;
                    pk[r] = (bf16_t)((o_acc[g][dt][r] + sm.r.Ored[qh][d * 68 + g * 16 + col]) * inv);
                }
                *(bf16x4*)(dst + dt * 16) = pk;
            }
        }
    }
}

// ---------------- output projection: 64x128 tiles, grid (8, 64) ----------------
__global__ __launch_bounds__(256, 3) void gemm_proj(
    const bf16_t* __restrict__ A2, const bf16_t* __restrict__ Wto,
    const float* __restrict__ bo, float* __restrict__ out)
{
    __shared__ bf16_t As[64 * 64];    // 8 KB
    __shared__ bf16_t Bs[128 * 64];   // 16 KB
    const int m0 = blockIdx.y * 64;
    const int n0 = blockIdx.x * 128;

    const int tid  = threadIdx.x;
    const int lane = tid & 63;
    const int wid  = tid >> 6;
    const int quad = lane >> 4;
    const int col  = lane & 15;
    const int wm   = (wid >> 1) * 32;
    const int wn   = (wid & 1) * 64;
    const int srow = tid >> 3;
    const int scc  = ((tid & 7) ^ (srow & 7)) * 8;
    const int xorc = col & 7;

    floatx4 acc[2][4];
#pragma unroll
    for (int i = 0; i < 2; ++i)
#pragma unroll
        for (int j = 0; j < 4; ++j)
            acc[i][j] = (floatx4){0.f, 0.f, 0.f, 0.f};

    const bf16_t* Ag = A2  + (size_t)(m0 + srow) * D_MODEL + scc;
    const bf16_t* Bg = Wto + (size_t)(n0 + srow) * D_MODEL + scc;
    bf16_t* Al = As + tid * 8;
    bf16_t* Bl = Bs + tid * 8;

    for (int kb = 0; kb < D_MODEL; kb += 64) {
#pragma unroll
        for (int p = 0; p < 2; ++p)
            async_copy16(Ag + kb + p * (32 * D_MODEL), Al + p * 2048);
#pragma unroll
        for (int p = 0; p < 4; ++p)
            async_copy16(Bg + kb + p * (32 * D_MODEL), Bl + p * 2048);
        __syncthreads();
#pragma unroll
        for (int kh = 0; kh < 2; ++kh) {
            bf16x8 af[2], bfr[4];
#pragma unroll
            for (int i = 0; i < 2; ++i)
                af[i] = *(const bf16x8*)(As + (wm + i * 16 + col) * 64 + (((kh * 4 + quad) ^ xorc) * 8));
#pragma unroll
            for (int j = 0; j < 4; ++j)
                bfr[j] = *(const bf16x8*)(Bs + (wn + j * 16 + col) * 64 + (((kh * 4 + quad) ^ xorc) * 8));
#pragma unroll
            for (int i = 0; i < 2; ++i)
#pragma unroll
                for (int j = 0; j < 4; ++j)
                    acc[i][j] = __builtin_amdgcn_mfma_f32_16x16x32_bf16(af[i], bfr[j], acc[i][j], 0, 0, 0);
        }
        __syncthreads();
    }

#pragma unroll
    for (int i = 0; i < 2; ++i) {
#pragma unroll
        for (int j = 0; j < 4; ++j) {
            const int n = n0 + wn + j * 16 + col;
            const float bb = bo[n];
#pragma unroll
            for (int r = 0; r < 4; ++r) {
                const int m = m0 + wm + i * 16 + quad * 4 + r;
                out[(size_t)m * D_MODEL + n] = acc[i][j][r] + bb;
            }
        }
    }
}

// ---------------- host ----------------
extern "C" void kernel_launch(void* const* d_in, const int* in_sizes, int n_in,
                              void* d_out, int out_size, void* d_ws, size_t ws_size,
                              hipStream_t stream) {
    const float* x  = (const float*)d_in[0];
    const float* Wq = (const float*)d_in[1];
    const float* bq = (const float*)d_in[2];
    const float* Wk = (const float*)d_in[3];
    const float* bk = (const float*)d_in[4];
    const float* Wv = (const float*)d_in[5];
    const float* bv = (const float*)d_in[6];
    const float* Wo = (const float*)d_in[7];
    const float* bo = (const float*)d_in[8];
    float* out = (float*)d_out;

    const size_t MB = 1ull << 20;
    char* ws = (char*)d_ws;
    bf16_t* Q     = (bf16_t*)(ws + 0 * MB);    // 8 MB  [b,h,s,d]
    bf16_t* Kh    = (bf16_t*)(ws + 8 * MB);    // 8 MB  [b,h,s,d]
    bf16_t* Vt    = (bf16_t*)(ws + 16 * MB);   // 8 MB  [b,h,d,s]
    bf16_t* A2    = (bf16_t*)(ws + 24 * MB);   // 8 MB  [b,s,h*d]
    bf16_t* xb    = (bf16_t*)(ws + 32 * MB);   // 8 MB
    bf16_t* Wtq   = (bf16_t*)(ws + 40 * MB);   // 2 MB each
    bf16_t* Wtk   = (bf16_t*)(ws + 42 * MB);
    bf16_t* Wtv   = (bf16_t*)(ws + 44 * MB);
    bf16_t* Wto   = (bf16_t*)(ws + 46 * MB);

    prep<<<dim3(32, 32, 5), dim3(32, 8), 0, stream>>>(
        x, xb, Wq, Wk, Wv, Wo, Wtq, Wtk, Wtv, Wto);

    gemm_qkv<<<dim3(D_MODEL / 128, MTOT / 128, 3), 256, 0, stream>>>(
        xb, Wtq, Wtk, Wtv, bq, bk, bv, Q, Kh, Vt);

    attn_kernel<<<dim3(512), 256, 0, stream>>>(Q, Kh, Vt, A2);

    gemm_proj<<<dim3(D_MODEL / 128, MTOT / 64), 256, 0, stream>>>(A2, Wto, bo, out);
}